// Round 6
// baseline (167.861 us; speedup 1.0000x reference)
//
#include <hip/hip_runtime.h>
#include <cfloat>

typedef unsigned long long u64;

#define CDESC 32
#define N0 4096
#define N1 512

// sign-transformed float bits: monotone u32 over the float total order
__device__ __forceinline__ unsigned fbits_mono(float d) {
    unsigned b = __float_as_uint(d);
    return (d >= 0.f) ? (b | 0x80000000u) : ~b;
}

__device__ __forceinline__ void wave_reduce_atomic(float v, float* acc) {
#pragma unroll
    for (int off = 32; off > 0; off >>= 1) v += __shfl_down(v, off, 64);
    if ((threadIdx.x & 63) == 0) atomicAdd(acc, v);
}

// ---------------- pass-1 body: x-filter (bit-exact since R1) ----------------
// in : [B*3][64][64][64]   out: [B*3][64][64][S]
template<int S, int R>
__device__ __forceinline__ void pass1_body(const float* __restrict__ in,
                                           float* __restrict__ out, int idx) {
    int xo = idx & (S - 1);
    int r  = idx / S;
    int y  = r & 63; r >>= 6;
    int z  = r & 63; r >>= 6;
    int bc = r;                                    // 0..11
    const float* row = in + (((bc * 64) + z) * 64 + y) * 64;
    constexpr int KW = 2 * R;
    int j0 = R * xo - R / 2;
    float sum = 0.f, wsum = 0.f;
#pragma unroll
    for (int t = 0; t < KW; ++t) {
        int j = j0 + t;
        float w = 1.f - fabsf((float)t - ((float)R - 0.5f)) / (float)R;
        if (j >= 0 && j < 64) { sum = fmaf(w, row[j], sum); wsum += w; }
    }
    out[idx] = sum / wsum;
}

// K1: both stages' x-filter; init acc, group tickets, argmin slots.
__global__ __launch_bounds__(256) void pass1_both(
        const float* __restrict__ csrc, const float* __restrict__ ctgt,
        float* __restrict__ t16a, float* __restrict__ t16b,
        float* __restrict__ t8a,  float* __restrict__ t8b,
        float* __restrict__ acc, unsigned* __restrict__ tick,
        u64* __restrict__ slot) {
    const float* in = blockIdx.y ? ctgt : csrc;
    if (blockIdx.y == 0) {                         // init side
        int gid = blockIdx.x * 256 + threadIdx.x;
        if (gid < 4) acc[gid] = 0.f;
        if (gid < 256) tick[gid] = 0u;
        if (gid < 16384) slot[gid] = ~0ull;        // poison 0xAA.. is NOT max — must init
    }
    if (blockIdx.x < 3072) {
        float* out = blockIdx.y ? t16b : t16a;
        pass1_body<16, 4>(in, out, blockIdx.x * 256 + threadIdx.x);
    } else {
        float* out = blockIdx.y ? t8b : t8a;
        pass1_body<8, 8>(in, out, (blockIdx.x - 3072) * 256 + threadIdx.x);
    }
}

// K2: both stages' y/z-filter, 8 sub-threads per point (occupancy: 1152 blocks).
// blocks 0..1023: stage-0 (1 z-tap/sub); blocks 1024..1151: stage-1 (2 z-taps/sub).
__global__ __launch_bounds__(256) void pass2_both(
        const float* __restrict__ t16a, const float* __restrict__ t16b,
        const float* __restrict__ t8a,  const float* __restrict__ t8b,
        float4* __restrict__ ps0, float4* __restrict__ pt0,
        float4* __restrict__ ps1, float4* __restrict__ pt1) {
    int gid = blockIdx.x * 256 + threadIdx.x;
    if (blockIdx.x < 1024) {
        // ---- stage 0: R=4, point p, sub-thread = one of 8 z-taps ----
        int sub = gid & 7, p = gid >> 3;           // p: 0..32767 (8 consecutive lanes/point)
        int side = p >> 14, r = p & 16383;
        int b = r >> 12, n = r & 4095;
        int x = n & 15, y = (n >> 4) & 15, z = n >> 8;
        const float* t = side ? t16b : t16a;
        float wy[8]; int jy[8];
        float wys = 0.f, wzs = 0.f;
#pragma unroll
        for (int tt = 0; tt < 8; ++tt) {
            float w = 1.f - fabsf((float)tt - 3.5f) * 0.25f;
            int j = 4 * y - 2 + tt;
            bool v = (unsigned)j < 64u;
            wy[tt] = v ? w : 0.f; jy[tt] = v ? j : 0; wys += wy[tt];
            int jz = 4 * z - 2 + tt;
            if ((unsigned)jz < 64u) wzs += w;
        }
        float a0 = 0.f, a1 = 0.f, a2 = 0.f;
        {
            float wz = 1.f - fabsf((float)sub - 3.5f) * 0.25f;
            int jz = 4 * z - 2 + sub;
            if ((unsigned)jz < 64u) {
                const float* bz = t + (size_t)b * 196608 + jz * 1024 + x;  // c-stride 65536
#pragma unroll
                for (int ty = 0; ty < 8; ++ty) {
                    float w = wz * wy[ty];
                    const float* pr = bz + jy[ty] * 16;
                    a0 = fmaf(w, pr[0],      a0);
                    a1 = fmaf(w, pr[65536],  a1);
                    a2 = fmaf(w, pr[131072], a2);
                }
            }
        }
#pragma unroll
        for (int m = 1; m < 8; m <<= 1) {          // 8 consecutive lanes: in-wave
            a0 += __shfl_xor(a0, m, 64);
            a1 += __shfl_xor(a1, m, 64);
            a2 += __shfl_xor(a2, m, 64);
        }
        if (sub == 0) {
            float inv = 1.f / (wys * wzs);
            a0 *= inv; a1 *= inv; a2 *= inv;
            float4* pts = side ? pt0 : ps0;
            pts[b * N0 + n] = make_float4(a0, a1, a2, a0 * a0 + a1 * a1 + a2 * a2);
        }
    } else {
        // ---- stage 1: R=8, 8 sub-threads/point, 2 z-taps each (verified R3/R5) ----
        int g = gid - 262144;
        int sub = g & 7, p = g >> 3;               // p: 0..4095
        int side = p >> 11, r = p & 2047;
        int b = r >> 9, n = r & 511;
        int x = n & 7, y = (n >> 3) & 7, z = n >> 6;
        const float* t = side ? t8b : t8a;
        constexpr int CS = 64 * 64 * 8;
        float wy[16]; int jy[16];
        float wys = 0.f, wzs = 0.f;
#pragma unroll
        for (int tt = 0; tt < 16; ++tt) {
            float w = 1.f - fabsf((float)tt - 7.5f) * 0.125f;
            int j = 8 * y - 4 + tt;
            bool v = (unsigned)j < 64u;
            wy[tt] = v ? w : 0.f; jy[tt] = v ? j : 0; wys += wy[tt];
            int jz = 8 * z - 4 + tt;
            if ((unsigned)jz < 64u) wzs += w;
        }
        float a0 = 0.f, a1 = 0.f, a2 = 0.f;
#pragma unroll
        for (int k = 0; k < 2; ++k) {
            int tt = 2 * sub + k;
            float wz = 1.f - fabsf((float)tt - 7.5f) * 0.125f;
            int jz = 8 * z - 4 + tt;
            if ((unsigned)jz < 64u) {
                const float* bz = t + b * 3 * CS + jz * (64 * 8) + x;
#pragma unroll 1
                for (int ty = 0; ty < 16; ++ty) {
                    float w = wz * wy[ty];
                    const float* pr = bz + jy[ty] * 8;
                    a0 = fmaf(w, pr[0],      a0);
                    a1 = fmaf(w, pr[CS],     a1);
                    a2 = fmaf(w, pr[2 * CS], a2);
                }
            }
        }
#pragma unroll
        for (int m = 1; m < 8; m <<= 1) {
            a0 += __shfl_xor(a0, m, 64);
            a1 += __shfl_xor(a1, m, 64);
            a2 += __shfl_xor(a2, m, 64);
        }
        if (sub == 0) {
            float inv = 1.f / (wys * wzs);
            a0 *= inv; a1 *= inv; a2 *= inv;
            float4* pts = side ? pt1 : ps1;
            pts[b * N1 + n] = make_float4(a0, a1, a2, a0 * a0 + a1 * a1 + a2 * a2);
        }
    }
}

// ======================= K3: argmin + cosine =======================
// blocks 0..1023: stage-0, block = (b, chunk, ntile). Stage 16 KB once, scan
//   256 m/thread (wave-uniform broadcast LDS reads), combine packed keys ->
//   atomicMin(slot). 4th-arriving block of each (b,ntile) group does the
//   cosine for its 64 points (slot read via device-scope atomic).
// blocks 1024..1031: stage-1 fused scan + cosine (verified R2/R5 body).
// Global 1032-ticket on acc[2] finalizes out.
__global__ __launch_bounds__(256) void nn_cos_all(
        const float4* __restrict__ ps0, const float4* __restrict__ pt0,
        const float* __restrict__ sd0, const float* __restrict__ td0,
        const float4* __restrict__ ps1, const float4* __restrict__ pt1,
        const float* __restrict__ sd1, const float* __restrict__ td1,
        u64* slot, unsigned* tick, float* acc, float* __restrict__ out) {
    __shared__ __align__(16) float4 sm[1024];      // 16 KB target tile
    __shared__ u64 keys[256];                      // combine keys / slot cache
    __shared__ float shN[256], shS[256], shT[256]; // cosine partials
    __shared__ int last_flag;
    const int tid = threadIdx.x;
    const int bx  = blockIdx.x;

    if (bx < 1024) {
        int b = bx >> 8, chunk = (bx >> 6) & 3, ntile = bx & 63;
        const float4* tp = pt0 + b * N0 + chunk * 1024;
        for (int i = tid; i < 1024; i += 256) {
            float4 q = tp[i];
            sm[i] = make_float4(-2.f * q.x, -2.f * q.y, -2.f * q.z, q.w);
        }
        __syncthreads();
        int p = tid & 63, q = tid >> 6;            // wave-uniform quarter q
        int n = ntile * 64 + p;
        float4 P = ps0[b * N0 + n];
        float best = FLT_MAX; int bi = 0;
        const int mb = q * 256;
#pragma unroll 8
        for (int k = 0; k < 256; ++k) {
            float4 Q = sm[mb + k];                 // broadcast, conflict-free
            float d = fmaf(P.x, Q.x, fmaf(P.y, Q.y, fmaf(P.z, Q.z, Q.w)));
            if (d < best) { best = d; bi = k; }    // ascending m: first-min
        }
        keys[tid] = ((u64)fbits_mono(best) << 32) | (unsigned)(chunk * 1024 + mb + bi);
        __syncthreads();
        if (tid < 64) {                            // wave 0: one lane per point
            u64 k0 = keys[tid],       k1 = keys[tid + 64];
            u64 k2 = keys[tid + 128], k3 = keys[tid + 192];
            u64 ka = k0 < k1 ? k0 : k1;
            u64 kb = k2 < k3 ? k2 : k3;
            atomicMin(&slot[b * N0 + ntile * 64 + tid], ka < kb ? ka : kb);
        }
        __syncthreads();
        if (tid == 0) {                            // group ticket: 4th block does cos
            __threadfence();
            last_flag = (atomicAdd(&tick[b * 64 + ntile], 1u) == 3u);
        }
        __syncthreads();
        if (last_flag) {
            if (tid < 64)                          // coherent device-scope read
                keys[tid] = atomicAdd(&slot[b * N0 + ntile * 64 + tid], 0ull);
            __syncthreads();
            int pp = tid & 63, qq = tid >> 6;      // 4 channel-quarters per point
            int nn = ntile * 64 + pp;
            int nearest = (int)(unsigned)(keys[pp] & 0xFFFFFFFFull);
            const float* s = sd0 + (size_t)b * CDESC * N0 + nn;
            const float* t = td0 + (size_t)b * CDESC * N0 + nearest;
            float num = 0.f, s2 = 0.f, t2 = 0.f;
#pragma unroll
            for (int c = qq * 8; c < qq * 8 + 8; ++c) {
                float a = s[c * N0], g = t[c * N0];
                num = fmaf(a, g, num); s2 = fmaf(a, a, s2); t2 = fmaf(g, g, t2);
            }
            shN[tid] = num; shS[tid] = s2; shT[tid] = t2;
            __syncthreads();
            if (tid < 64) {
                float nm = shN[tid] + shN[tid + 64] + shN[tid + 128] + shN[tid + 192];
                float a2 = shS[tid] + shS[tid + 64] + shS[tid + 128] + shS[tid + 192];
                float b2 = shT[tid] + shT[tid + 64] + shT[tid + 128] + shT[tid + 192];
                float cosv = nm / (fmaxf(sqrtf(a2), 1e-8f) * fmaxf(sqrtf(b2), 1e-8f));
                wave_reduce_atomic(cosv, acc + 0);
            }
        }
    } else {
        int bb = bx - 1024;
        int b = bb >> 1;
        const float4* tp = pt1 + b * N1;
        for (int i = tid; i < N1; i += 256) {
            float4 qq = tp[i];
            sm[i] = make_float4(-2.f * qq.x, -2.f * qq.y, -2.f * qq.z, qq.w);
        }
        __syncthreads();
        int n = (bb & 1) * 256 + tid;
        float4 P = ps1[b * N1 + n];
        float best = FLT_MAX; int bi = 0;
#pragma unroll 8
        for (int m = 0; m < N1; ++m) {
            float4 Q = sm[m];
            float d = fmaf(P.x, Q.x, fmaf(P.y, Q.y, fmaf(P.z, Q.z, Q.w)));
            if (d < best) { best = d; bi = m; }    // ascending m: first-min
        }
        const float* s = sd1 + (size_t)b * CDESC * N1 + n;
        const float* t = td1 + (size_t)b * CDESC * N1 + bi;
        float num = 0.f, s2 = 0.f, t2 = 0.f;
#pragma unroll
        for (int c = 0; c < CDESC; ++c) {
            float a = s[c * N1], g = t[c * N1];
            num = fmaf(a, g, num); s2 = fmaf(a, a, s2); t2 = fmaf(g, g, t2);
        }
        float denom = fmaxf(sqrtf(s2), 1e-8f) * fmaxf(sqrtf(t2), 1e-8f);
        wave_reduce_atomic(num / denom, acc + 1);
    }

    __syncthreads();                               // block's atomics all issued
    if (tid == 0) {
        __threadfence();
        unsigned old = atomicAdd((unsigned*)(acc + 2), 1u);
        if (old == 1031u) {                        // last of 1032 blocks
            float a0 = atomicAdd(acc + 0, 0.f);    // coherent reads
            float a1 = atomicAdd(acc + 1, 0.f);
            out[0] = 1.f - 0.5f * (a0 * (1.f / 16384.f) + a1 * (1.f / 2048.f));
        }
    }
}

extern "C" void kernel_launch(void* const* d_in, const int* in_sizes, int n_in,
                              void* d_out, int out_size, void* d_ws, size_t ws_size,
                              hipStream_t stream) {
    const float* c_src = (const float*)d_in[0];   // [4,3,64,64,64]
    const float* c_tgt = (const float*)d_in[1];
    const float* sd0   = (const float*)d_in[2];   // [4,32,16,16,16]
    const float* td0   = (const float*)d_in[3];
    const float* sd1   = (const float*)d_in[4];   // [4,32,8,8,8]
    const float* td1   = (const float*)d_in[5];
    float* out = (float*)d_out;

    char* ws = (char*)d_ws;
    float*    acc  = (float*)ws;                   // [0]=sum0 [1]=sum1 [2]=global ticket
    unsigned* tick = (unsigned*)(ws + 256);        // 256 group tickets
    u64*      slot = (u64*)(ws + 2048);            // 16384 u64 (128 KB)
    float* t16a = (float*)(ws + 2048 + 131072);    // 786432 floats each
    float* t16b = t16a + 786432;
    float* t8a  = t16b + 786432;                   // 393216 floats each
    float* t8b  = t8a + 393216;
    float4* ps0 = (float4*)(t8b + 393216);         // 16384 float4 (16B-aligned)
    float4* pt0 = ps0 + 16384;
    float4* ps1 = pt0 + 16384;                     // 2048 float4
    float4* pt1 = ps1 + 2048;

    pass1_both<<<dim3(4608, 2), 256, 0, stream>>>(c_src, c_tgt, t16a, t16b, t8a, t8b,
                                                  acc, tick, slot);
    pass2_both<<<1152, 256, 0, stream>>>(t16a, t16b, t8a, t8b, ps0, pt0, ps1, pt1);
    nn_cos_all<<<1032, 256, 0, stream>>>(ps0, pt0, sd0, td0, ps1, pt1, sd1, td1,
                                         slot, tick, acc, out);
}

// Round 7
// 161.960 us; speedup vs baseline: 1.0364x; 1.0364x over previous
//
#include <hip/hip_runtime.h>
#include <cfloat>

typedef unsigned long long u64;

#define CDESC 32
#define N0 4096
#define N1 512

// sign-transformed float bits: monotone u32 over the float total order
__device__ __forceinline__ unsigned fbits_mono(float d) {
    unsigned b = __float_as_uint(d);
    return (d >= 0.f) ? (b | 0x80000000u) : ~b;
}

__device__ __forceinline__ void wave_reduce_atomic(float v, float* acc) {
#pragma unroll
    for (int off = 32; off > 0; off >>= 1) v += __shfl_down(v, off, 64);
    if ((threadIdx.x & 63) == 0) atomicAdd(acc, v);
}

// ---------------- pass-1 body: x-filter (bit-exact since R1) ----------------
template<int S, int R>
__device__ __forceinline__ void pass1_body(const float* __restrict__ in,
                                           float* __restrict__ out, int idx) {
    int xo = idx & (S - 1);
    int r  = idx / S;
    int y  = r & 63; r >>= 6;
    int z  = r & 63; r >>= 6;
    int bc = r;                                    // 0..11
    const float* row = in + (((bc * 64) + z) * 64 + y) * 64;
    constexpr int KW = 2 * R;
    int j0 = R * xo - R / 2;
    float sum = 0.f, wsum = 0.f;
#pragma unroll
    for (int t = 0; t < KW; ++t) {
        int j = j0 + t;
        float w = 1.f - fabsf((float)t - ((float)R - 0.5f)) / (float)R;
        if (j >= 0 && j < 64) { sum = fmaf(w, row[j], sum); wsum += w; }
    }
    out[idx] = sum / wsum;
}

// K1: x-filter (blocks 0..4607) + descriptor transposes to point-major
// (blocks 4608..4895) + init acc/tick/slot. blockIdx.y = side (src/tgt).
__global__ __launch_bounds__(256) void pass1_both(
        const float* __restrict__ csrc, const float* __restrict__ ctgt,
        const float* __restrict__ sd0, const float* __restrict__ td0,
        const float* __restrict__ sd1, const float* __restrict__ td1,
        float* __restrict__ t16a, float* __restrict__ t16b,
        float* __restrict__ t8a,  float* __restrict__ t8b,
        float* __restrict__ sd0T, float* __restrict__ td0T,
        float* __restrict__ sd1T, float* __restrict__ td1T,
        float* __restrict__ acc, unsigned* __restrict__ tick,
        u64* __restrict__ slot) {
    __shared__ float tile[64 * 33];                // transpose tile (+1 pad)
    const int tid = threadIdx.x;
    const int bx  = blockIdx.x, by = blockIdx.y;
    if (by == 0) {                                 // init side
        int gid = bx * 256 + tid;
        if (gid < 4) acc[gid] = 0.f;
        if (gid < 256) tick[gid] = 0u;
        if (gid < 16384) slot[gid] = ~0ull;        // 0xAA poison is NOT max — must init
    }
    if (bx < 3072) {
        pass1_body<16, 4>(by ? ctgt : csrc, by ? t16b : t16a, bx * 256 + tid);
    } else if (bx < 4608) {
        pass1_body<8, 8>(by ? ctgt : csrc, by ? t8b : t8a, (bx - 3072) * 256 + tid);
    } else {
        // ---- transpose [b][32][N] -> [b][N][32], 64-point tiles ----
        int tl = bx - 4608;                        // 0..287
        const float* din; float* dout; int N, b, n0;
        if (tl < 256) { din = by ? td0 : sd0; dout = by ? td0T : sd0T;
                        N = N0; b = tl >> 6; n0 = (tl & 63) * 64; }
        else { tl -= 256; din = by ? td1 : sd1; dout = by ? td1T : sd1T;
               N = N1; b = tl >> 3; n0 = (tl & 7) * 64; }
#pragma unroll
        for (int i = 0; i < 8; ++i) {              // load: coalesced 64-float rows
            int idx = tid + i * 256;
            int c = idx >> 6, j = idx & 63;
            tile[j * 33 + c] = din[((size_t)b * CDESC + c) * N + n0 + j];
        }
        __syncthreads();
#pragma unroll
        for (int i = 0; i < 8; ++i) {              // store: contiguous 32-float points
            int idx = tid + i * 256;
            int p = idx >> 5, c = idx & 31;
            dout[((size_t)b * N + n0 + p) * CDESC + c] = tile[p * 33 + c];
        }
    }
}

// K2: both stages' y/z-filter, 8 sub-threads per point (verified R6).
__global__ __launch_bounds__(256) void pass2_both(
        const float* __restrict__ t16a, const float* __restrict__ t16b,
        const float* __restrict__ t8a,  const float* __restrict__ t8b,
        float4* __restrict__ ps0, float4* __restrict__ pt0,
        float4* __restrict__ ps1, float4* __restrict__ pt1) {
    int gid = blockIdx.x * 256 + threadIdx.x;
    if (blockIdx.x < 1024) {
        int sub = gid & 7, p = gid >> 3;
        int side = p >> 14, r = p & 16383;
        int b = r >> 12, n = r & 4095;
        int x = n & 15, y = (n >> 4) & 15, z = n >> 8;
        const float* t = side ? t16b : t16a;
        float wy[8]; int jy[8];
        float wys = 0.f, wzs = 0.f;
#pragma unroll
        for (int tt = 0; tt < 8; ++tt) {
            float w = 1.f - fabsf((float)tt - 3.5f) * 0.25f;
            int j = 4 * y - 2 + tt;
            bool v = (unsigned)j < 64u;
            wy[tt] = v ? w : 0.f; jy[tt] = v ? j : 0; wys += wy[tt];
            int jz = 4 * z - 2 + tt;
            if ((unsigned)jz < 64u) wzs += w;
        }
        float a0 = 0.f, a1 = 0.f, a2 = 0.f;
        {
            float wz = 1.f - fabsf((float)sub - 3.5f) * 0.25f;
            int jz = 4 * z - 2 + sub;
            if ((unsigned)jz < 64u) {
                const float* bz = t + (size_t)b * 196608 + jz * 1024 + x;
#pragma unroll
                for (int ty = 0; ty < 8; ++ty) {
                    float w = wz * wy[ty];
                    const float* pr = bz + jy[ty] * 16;
                    a0 = fmaf(w, pr[0],      a0);
                    a1 = fmaf(w, pr[65536],  a1);
                    a2 = fmaf(w, pr[131072], a2);
                }
            }
        }
#pragma unroll
        for (int m = 1; m < 8; m <<= 1) {
            a0 += __shfl_xor(a0, m, 64);
            a1 += __shfl_xor(a1, m, 64);
            a2 += __shfl_xor(a2, m, 64);
        }
        if (sub == 0) {
            float inv = 1.f / (wys * wzs);
            a0 *= inv; a1 *= inv; a2 *= inv;
            float4* pts = side ? pt0 : ps0;
            pts[b * N0 + n] = make_float4(a0, a1, a2, a0 * a0 + a1 * a1 + a2 * a2);
        }
    } else {
        int g = gid - 262144;
        int sub = g & 7, p = g >> 3;
        int side = p >> 11, r = p & 2047;
        int b = r >> 9, n = r & 511;
        int x = n & 7, y = (n >> 3) & 7, z = n >> 6;
        const float* t = side ? t8b : t8a;
        constexpr int CS = 64 * 64 * 8;
        float wy[16]; int jy[16];
        float wys = 0.f, wzs = 0.f;
#pragma unroll
        for (int tt = 0; tt < 16; ++tt) {
            float w = 1.f - fabsf((float)tt - 7.5f) * 0.125f;
            int j = 8 * y - 4 + tt;
            bool v = (unsigned)j < 64u;
            wy[tt] = v ? w : 0.f; jy[tt] = v ? j : 0; wys += wy[tt];
            int jz = 8 * z - 4 + tt;
            if ((unsigned)jz < 64u) wzs += w;
        }
        float a0 = 0.f, a1 = 0.f, a2 = 0.f;
#pragma unroll
        for (int k = 0; k < 2; ++k) {
            int tt = 2 * sub + k;
            float wz = 1.f - fabsf((float)tt - 7.5f) * 0.125f;
            int jz = 8 * z - 4 + tt;
            if ((unsigned)jz < 64u) {
                const float* bz = t + b * 3 * CS + jz * (64 * 8) + x;
#pragma unroll 1
                for (int ty = 0; ty < 16; ++ty) {
                    float w = wz * wy[ty];
                    const float* pr = bz + jy[ty] * 8;
                    a0 = fmaf(w, pr[0],      a0);
                    a1 = fmaf(w, pr[CS],     a1);
                    a2 = fmaf(w, pr[2 * CS], a2);
                }
            }
        }
#pragma unroll
        for (int m = 1; m < 8; m <<= 1) {
            a0 += __shfl_xor(a0, m, 64);
            a1 += __shfl_xor(a1, m, 64);
            a2 += __shfl_xor(a2, m, 64);
        }
        if (sub == 0) {
            float inv = 1.f / (wys * wzs);
            a0 *= inv; a1 *= inv; a2 *= inv;
            float4* pts = side ? pt1 : ps1;
            pts[b * N1 + n] = make_float4(a0, a1, a2, a0 * a0 + a1 * a1 + a2 * a2);
        }
    }
}

// cosine of two point-major 32-float descriptors (coalesced float4 reads)
__device__ __forceinline__ float cos_pm(const float* __restrict__ sT,
                                        const float* __restrict__ tT,
                                        size_t si, size_t ti) {
    const float4* s = (const float4*)(sT + si * CDESC);
    const float4* t = (const float4*)(tT + ti * CDESC);
    float num = 0.f, s2 = 0.f, t2 = 0.f;
#pragma unroll
    for (int c = 0; c < 8; ++c) {
        float4 a = s[c], g = t[c];
        num = fmaf(a.x, g.x, fmaf(a.y, g.y, fmaf(a.z, g.z, fmaf(a.w, g.w, num))));
        s2  = fmaf(a.x, a.x, fmaf(a.y, a.y, fmaf(a.z, a.z, fmaf(a.w, a.w, s2))));
        t2  = fmaf(g.x, g.x, fmaf(g.y, g.y, fmaf(g.z, g.z, fmaf(g.w, g.w, t2))));
    }
    return num / (fmaxf(sqrtf(s2), 1e-8f) * fmaxf(sqrtf(t2), 1e-8f));
}

// ======================= K3: argmin + cosine =======================
// blocks 0..1023: stage-0, block = (b, chunk, ntile). Stage 16 KB once, scan
//   256 m/thread (wave-uniform broadcast LDS reads), combine packed keys ->
//   atomicMin(slot). 4th-arriving block of each (b,ntile) group does the
//   cosine for its 64 points with POINT-MAJOR descriptors (coalesced).
// blocks 1024..1031: stage-1 fused scan + cosine (point-major).
// Global 1032-ticket on acc[2] finalizes out.
__global__ __launch_bounds__(256) void nn_cos_all(
        const float4* __restrict__ ps0, const float4* __restrict__ pt0,
        const float* __restrict__ sd0T, const float* __restrict__ td0T,
        const float4* __restrict__ ps1, const float4* __restrict__ pt1,
        const float* __restrict__ sd1T, const float* __restrict__ td1T,
        u64* slot, unsigned* tick, float* acc, float* __restrict__ out) {
    __shared__ __align__(16) float4 sm[1024];      // 16 KB target tile
    __shared__ u64 keys[256];
    __shared__ int last_flag;
    const int tid = threadIdx.x;
    const int bx  = blockIdx.x;

    if (bx < 1024) {
        int b = bx >> 8, chunk = (bx >> 6) & 3, ntile = bx & 63;
        const float4* tp = pt0 + b * N0 + chunk * 1024;
        for (int i = tid; i < 1024; i += 256) {
            float4 q = tp[i];
            sm[i] = make_float4(-2.f * q.x, -2.f * q.y, -2.f * q.z, q.w);
        }
        __syncthreads();
        int p = tid & 63, q = tid >> 6;            // wave-uniform quarter q
        int n = ntile * 64 + p;
        float4 P = ps0[b * N0 + n];
        float best = FLT_MAX; int bi = 0;
        const int mb = q * 256;
#pragma unroll 8
        for (int k = 0; k < 256; ++k) {
            float4 Q = sm[mb + k];                 // broadcast, conflict-free
            float d = fmaf(P.x, Q.x, fmaf(P.y, Q.y, fmaf(P.z, Q.z, Q.w)));
            if (d < best) { best = d; bi = k; }    // ascending m: first-min
        }
        keys[tid] = ((u64)fbits_mono(best) << 32) | (unsigned)(chunk * 1024 + mb + bi);
        __syncthreads();
        if (tid < 64) {                            // wave 0: one lane per point
            u64 k0 = keys[tid],       k1 = keys[tid + 64];
            u64 k2 = keys[tid + 128], k3 = keys[tid + 192];
            u64 ka = k0 < k1 ? k0 : k1;
            u64 kb = k2 < k3 ? k2 : k3;
            atomicMin(&slot[b * N0 + ntile * 64 + tid], ka < kb ? ka : kb);
        }
        __syncthreads();
        if (tid == 0) {                            // group ticket: 4th block does cos
            __threadfence();
            last_flag = (atomicAdd(&tick[b * 64 + ntile], 1u) == 3u);
        }
        __syncthreads();
        if (last_flag && tid < 64) {
            int n2 = ntile * 64 + tid;
            u64 kk = atomicAdd(&slot[b * N0 + n2], 0ull);   // coherent read
            int nearest = (int)(unsigned)(kk & 0xFFFFFFFFull);
            float cosv = cos_pm(sd0T, td0T, (size_t)b * N0 + n2, (size_t)b * N0 + nearest);
            wave_reduce_atomic(cosv, acc + 0);
        }
    } else {
        int bb = bx - 1024;
        int b = bb >> 1;
        const float4* tp = pt1 + b * N1;
        for (int i = tid; i < N1; i += 256) {
            float4 qq = tp[i];
            sm[i] = make_float4(-2.f * qq.x, -2.f * qq.y, -2.f * qq.z, qq.w);
        }
        __syncthreads();
        int n = (bb & 1) * 256 + tid;
        float4 P = ps1[b * N1 + n];
        float best = FLT_MAX; int bi = 0;
#pragma unroll 8
        for (int m = 0; m < N1; ++m) {
            float4 Q = sm[m];
            float d = fmaf(P.x, Q.x, fmaf(P.y, Q.y, fmaf(P.z, Q.z, Q.w)));
            if (d < best) { best = d; bi = m; }    // ascending m: first-min
        }
        float cosv = cos_pm(sd1T, td1T, (size_t)b * N1 + n, (size_t)b * N1 + bi);
        wave_reduce_atomic(cosv, acc + 1);
    }

    __syncthreads();                               // block's atomics all issued
    if (tid == 0) {
        __threadfence();
        unsigned old = atomicAdd((unsigned*)(acc + 2), 1u);
        if (old == 1031u) {                        // last of 1032 blocks
            float a0 = atomicAdd(acc + 0, 0.f);
            float a1 = atomicAdd(acc + 1, 0.f);
            out[0] = 1.f - 0.5f * (a0 * (1.f / 16384.f) + a1 * (1.f / 2048.f));
        }
    }
}

extern "C" void kernel_launch(void* const* d_in, const int* in_sizes, int n_in,
                              void* d_out, int out_size, void* d_ws, size_t ws_size,
                              hipStream_t stream) {
    const float* c_src = (const float*)d_in[0];   // [4,3,64,64,64]
    const float* c_tgt = (const float*)d_in[1];
    const float* sd0   = (const float*)d_in[2];   // [4,32,16,16,16]
    const float* td0   = (const float*)d_in[3];
    const float* sd1   = (const float*)d_in[4];   // [4,32,8,8,8]
    const float* td1   = (const float*)d_in[5];
    float* out = (float*)d_out;

    char* ws = (char*)d_ws;
    float*    acc  = (float*)ws;                   // [0]=sum0 [1]=sum1 [2]=global ticket
    unsigned* tick = (unsigned*)(ws + 256);        // 256 group tickets
    u64*      slot = (u64*)(ws + 2048);            // 16384 u64 (128 KB)
    float* t16a = (float*)(ws + 2048 + 131072);    // 786432 floats each
    float* t16b = t16a + 786432;
    float* t8a  = t16b + 786432;                   // 393216 floats each
    float* t8b  = t8a + 393216;
    float4* ps0 = (float4*)(t8b + 393216);         // 16384 float4
    float4* pt0 = ps0 + 16384;
    float4* ps1 = pt0 + 16384;                     // 2048 float4
    float4* pt1 = ps1 + 2048;
    float* sd0T = (float*)(pt1 + 2048);            // 524288 floats each (16B-aligned)
    float* td0T = sd0T + 524288;
    float* sd1T = td0T + 524288;                   // 65536 floats each
    float* td1T = sd1T + 65536;

    pass1_both<<<dim3(4896, 2), 256, 0, stream>>>(c_src, c_tgt, sd0, td0, sd1, td1,
                                                  t16a, t16b, t8a, t8b,
                                                  sd0T, td0T, sd1T, td1T,
                                                  acc, tick, slot);
    pass2_both<<<1152, 256, 0, stream>>>(t16a, t16b, t8a, t8b, ps0, pt0, ps1, pt1);
    nn_cos_all<<<1032, 256, 0, stream>>>(ps0, pt0, sd0T, td0T, ps1, pt1, sd1T, td1T,
                                         slot, tick, acc, out);
}

// Round 8
// 142.932 us; speedup vs baseline: 1.1744x; 1.1331x over previous
//
#include <hip/hip_runtime.h>
#include <cfloat>

typedef unsigned long long u64;

#define CDESC 32
#define N0 4096
#define N1 512

// sign-transformed float bits: monotone u32 over the float total order
__device__ __forceinline__ unsigned fbits_mono(float d) {
    unsigned b = __float_as_uint(d);
    return (d >= 0.f) ? (b | 0x80000000u) : ~b;
}

__device__ __forceinline__ void wave_reduce_atomic(float v, float* acc) {
#pragma unroll
    for (int off = 32; off > 0; off >>= 1) v += __shfl_down(v, off, 64);
    if ((threadIdx.x & 63) == 0) atomicAdd(acc, v);
}

// ---------------- pass-1 body: x-filter (bit-exact since R1) ----------------
template<int S, int R>
__device__ __forceinline__ void pass1_body(const float* __restrict__ in,
                                           float* __restrict__ out, int idx) {
    int xo = idx & (S - 1);
    int r  = idx / S;
    int y  = r & 63; r >>= 6;
    int z  = r & 63; r >>= 6;
    int bc = r;                                    // 0..11
    const float* row = in + (((bc * 64) + z) * 64 + y) * 64;
    constexpr int KW = 2 * R;
    int j0 = R * xo - R / 2;
    float sum = 0.f, wsum = 0.f;
#pragma unroll
    for (int t = 0; t < KW; ++t) {
        int j = j0 + t;
        float w = 1.f - fabsf((float)t - ((float)R - 0.5f)) / (float)R;
        if (j >= 0 && j < 64) { sum = fmaf(w, row[j], sum); wsum += w; }
    }
    out[idx] = sum / wsum;
}

// K1: x-filter (blocks 0..4607) + descriptor transpose to point-major
// (blocks 4608..4895) + init acc. blockIdx.y = side (src/tgt).
__global__ __launch_bounds__(256) void pass1_both(
        const float* __restrict__ csrc, const float* __restrict__ ctgt,
        const float* __restrict__ sd0, const float* __restrict__ td0,
        const float* __restrict__ sd1, const float* __restrict__ td1,
        float* __restrict__ t16a, float* __restrict__ t16b,
        float* __restrict__ t8a,  float* __restrict__ t8b,
        float* __restrict__ sd0T, float* __restrict__ td0T,
        float* __restrict__ sd1T, float* __restrict__ td1T,
        float* __restrict__ acc) {
    __shared__ float tile[64 * 33];                // transpose tile (+1 pad)
    const int tid = threadIdx.x;
    const int bx  = blockIdx.x, by = blockIdx.y;
    if (by == 0 && bx == 0 && tid < 4) acc[tid] = 0.f;
    if (bx < 3072) {
        pass1_body<16, 4>(by ? ctgt : csrc, by ? t16b : t16a, bx * 256 + tid);
    } else if (bx < 4608) {
        pass1_body<8, 8>(by ? ctgt : csrc, by ? t8b : t8a, (bx - 3072) * 256 + tid);
    } else {
        // ---- transpose [b][32][N] -> [b][N][32], 64-point tiles ----
        int tl = bx - 4608;                        // 0..287
        const float* din; float* dout; int N, b, n0;
        if (tl < 256) { din = by ? td0 : sd0; dout = by ? td0T : sd0T;
                        N = N0; b = tl >> 6; n0 = (tl & 63) * 64; }
        else { tl -= 256; din = by ? td1 : sd1; dout = by ? td1T : sd1T;
               N = N1; b = tl >> 3; n0 = (tl & 7) * 64; }
#pragma unroll
        for (int i = 0; i < 8; ++i) {              // load: coalesced 64-float rows
            int idx = tid + i * 256;
            int c = idx >> 6, j = idx & 63;
            tile[j * 33 + c] = din[((size_t)b * CDESC + c) * N + n0 + j];
        }
        __syncthreads();
#pragma unroll
        for (int i = 0; i < 8; ++i) {              // store: contiguous 32-float points
            int idx = tid + i * 256;
            int p = idx >> 5, c = idx & 31;
            dout[((size_t)b * N + n0 + p) * CDESC + c] = tile[p * 33 + c];
        }
    }
}

// K2: both stages' y/z-filter, 8 sub-threads per point (verified R6/R7).
__global__ __launch_bounds__(256) void pass2_both(
        const float* __restrict__ t16a, const float* __restrict__ t16b,
        const float* __restrict__ t8a,  const float* __restrict__ t8b,
        float4* __restrict__ ps0, float4* __restrict__ pt0,
        float4* __restrict__ ps1, float4* __restrict__ pt1) {
    int gid = blockIdx.x * 256 + threadIdx.x;
    if (blockIdx.x < 1024) {
        int sub = gid & 7, p = gid >> 3;
        int side = p >> 14, r = p & 16383;
        int b = r >> 12, n = r & 4095;
        int x = n & 15, y = (n >> 4) & 15, z = n >> 8;
        const float* t = side ? t16b : t16a;
        float wy[8]; int jy[8];
        float wys = 0.f, wzs = 0.f;
#pragma unroll
        for (int tt = 0; tt < 8; ++tt) {
            float w = 1.f - fabsf((float)tt - 3.5f) * 0.25f;
            int j = 4 * y - 2 + tt;
            bool v = (unsigned)j < 64u;
            wy[tt] = v ? w : 0.f; jy[tt] = v ? j : 0; wys += wy[tt];
            int jz = 4 * z - 2 + tt;
            if ((unsigned)jz < 64u) wzs += w;
        }
        float a0 = 0.f, a1 = 0.f, a2 = 0.f;
        {
            float wz = 1.f - fabsf((float)sub - 3.5f) * 0.25f;
            int jz = 4 * z - 2 + sub;
            if ((unsigned)jz < 64u) {
                const float* bz = t + (size_t)b * 196608 + jz * 1024 + x;
#pragma unroll
                for (int ty = 0; ty < 8; ++ty) {
                    float w = wz * wy[ty];
                    const float* pr = bz + jy[ty] * 16;
                    a0 = fmaf(w, pr[0],      a0);
                    a1 = fmaf(w, pr[65536],  a1);
                    a2 = fmaf(w, pr[131072], a2);
                }
            }
        }
#pragma unroll
        for (int m = 1; m < 8; m <<= 1) {
            a0 += __shfl_xor(a0, m, 64);
            a1 += __shfl_xor(a1, m, 64);
            a2 += __shfl_xor(a2, m, 64);
        }
        if (sub == 0) {
            float inv = 1.f / (wys * wzs);
            a0 *= inv; a1 *= inv; a2 *= inv;
            float4* pts = side ? pt0 : ps0;
            pts[b * N0 + n] = make_float4(a0, a1, a2, a0 * a0 + a1 * a1 + a2 * a2);
        }
    } else {
        int g = gid - 262144;
        int sub = g & 7, p = g >> 3;
        int side = p >> 11, r = p & 2047;
        int b = r >> 9, n = r & 511;
        int x = n & 7, y = (n >> 3) & 7, z = n >> 6;
        const float* t = side ? t8b : t8a;
        constexpr int CS = 64 * 64 * 8;
        float wy[16]; int jy[16];
        float wys = 0.f, wzs = 0.f;
#pragma unroll
        for (int tt = 0; tt < 16; ++tt) {
            float w = 1.f - fabsf((float)tt - 7.5f) * 0.125f;
            int j = 8 * y - 4 + tt;
            bool v = (unsigned)j < 64u;
            wy[tt] = v ? w : 0.f; jy[tt] = v ? j : 0; wys += wy[tt];
            int jz = 8 * z - 4 + tt;
            if ((unsigned)jz < 64u) wzs += w;
        }
        float a0 = 0.f, a1 = 0.f, a2 = 0.f;
#pragma unroll
        for (int k = 0; k < 2; ++k) {
            int tt = 2 * sub + k;
            float wz = 1.f - fabsf((float)tt - 7.5f) * 0.125f;
            int jz = 8 * z - 4 + tt;
            if ((unsigned)jz < 64u) {
                const float* bz = t + b * 3 * CS + jz * (64 * 8) + x;
#pragma unroll 1
                for (int ty = 0; ty < 16; ++ty) {
                    float w = wz * wy[ty];
                    const float* pr = bz + jy[ty] * 8;
                    a0 = fmaf(w, pr[0],      a0);
                    a1 = fmaf(w, pr[CS],     a1);
                    a2 = fmaf(w, pr[2 * CS], a2);
                }
            }
        }
#pragma unroll
        for (int m = 1; m < 8; m <<= 1) {
            a0 += __shfl_xor(a0, m, 64);
            a1 += __shfl_xor(a1, m, 64);
            a2 += __shfl_xor(a2, m, 64);
        }
        if (sub == 0) {
            float inv = 1.f / (wys * wzs);
            a0 *= inv; a1 *= inv; a2 *= inv;
            float4* pts = side ? pt1 : ps1;
            pts[b * N1 + n] = make_float4(a0, a1, a2, a0 * a0 + a1 * a1 + a2 * a2);
        }
    }
}

// cosine of two point-major 32-float descriptors (coalesced float4 reads)
__device__ __forceinline__ float cos_pm(const float* __restrict__ sT,
                                        const float* __restrict__ tT,
                                        size_t si, size_t ti) {
    const float4* s = (const float4*)(sT + si * CDESC);
    const float4* t = (const float4*)(tT + ti * CDESC);
    float num = 0.f, s2 = 0.f, t2 = 0.f;
#pragma unroll
    for (int c = 0; c < 8; ++c) {
        float4 a = s[c], g = t[c];
        num = fmaf(a.x, g.x, fmaf(a.y, g.y, fmaf(a.z, g.z, fmaf(a.w, g.w, num))));
        s2  = fmaf(a.x, a.x, fmaf(a.y, a.y, fmaf(a.z, a.z, fmaf(a.w, a.w, s2))));
        t2  = fmaf(g.x, g.x, fmaf(g.y, g.y, fmaf(g.z, g.z, fmaf(g.w, g.w, t2))));
    }
    return num / (fmaxf(sqrtf(s2), 1e-8f) * fmaxf(sqrtf(t2), 1e-8f));
}

// ======================= K3: argmin + cosine, fully block-local =======================
// blocks 0..255: stage-0, block = (b, 64-point tile). ALL 4096 targets staged to
//   64 KB dynamic LDS once; 4 waves split m into 4x1024 windows; lane = point.
//   Broadcast ds_read_b128 (conflict-free), 16-deep load batching for latency.
//   Cross-wave combine via packed (mono(d)<<32 | m) keys in LDS (reused target
//   buffer) == lexicographic (d,m) min == jnp.argmin first-min. Then point-major
//   coalesced cosine. NO cross-block atomics in the scan path.
// blocks 256..263: stage-1 fused scan + cosine (verified body).
// Global 264-ticket on acc[2] finalizes out.
__global__ __launch_bounds__(256) void nn_cos_all(
        const float4* __restrict__ ps0, const float4* __restrict__ pt0,
        const float* __restrict__ sd0T, const float* __restrict__ td0T,
        const float4* __restrict__ ps1, const float4* __restrict__ pt1,
        const float* __restrict__ sd1T, const float* __restrict__ td1T,
        float* acc, float* __restrict__ out) {
    extern __shared__ __align__(16) char smraw[];  // 64 KB dynamic
    float4* sm = (float4*)smraw;
    const int tid = threadIdx.x;
    const int bx  = blockIdx.x;

    if (bx < 256) {
        int b = bx >> 6, ptile = bx & 63;
        const float4* tp = pt0 + b * N0;
        for (int i = tid; i < N0; i += 256) {      // stage all 4096 targets (64 KB)
            float4 q = tp[i];
            sm[i] = make_float4(-2.f * q.x, -2.f * q.y, -2.f * q.z, q.w);
        }
        __syncthreads();
        int w = tid >> 6, lane = tid & 63;
        int n = ptile * 64 + lane;
        float4 P = ps0[b * N0 + n];
        float best = FLT_MAX; int bi = 0;
        const int m0 = w * 1024;                   // this wave's m-window
#pragma unroll 16
        for (int k = 0; k < 1024; ++k) {
            float4 Q = sm[m0 + k];                 // broadcast, conflict-free
            float d = fmaf(P.x, Q.x, fmaf(P.y, Q.y, fmaf(P.z, Q.z, Q.w)));
            if (d < best) { best = d; bi = k; }    // ascending m: first-min
        }
        u64 key = ((u64)fbits_mono(best) << 32) | (unsigned)(m0 + bi);
        __syncthreads();                           // everyone done reading sm
        u64* keys = (u64*)smraw;                   // reuse LDS for combine
        keys[w * 64 + lane] = key;
        __syncthreads();
        if (tid < 64) {
            u64 k0 = keys[tid],       k1 = keys[tid + 64];
            u64 k2 = keys[tid + 128], k3 = keys[tid + 192];
            u64 ka = k0 < k1 ? k0 : k1;
            u64 kb = k2 < k3 ? k2 : k3;
            u64 kk = ka < kb ? ka : kb;            // windows ascending + u64 min
            int nearest = (int)(unsigned)(kk & 0xFFFFFFFFull);
            int n2 = ptile * 64 + tid;
            float cosv = cos_pm(sd0T, td0T, (size_t)b * N0 + n2,
                                (size_t)b * N0 + nearest);
            wave_reduce_atomic(cosv, acc + 0);
        }
    } else {
        int bb = bx - 256;
        int b = bb >> 1;
        const float4* tp = pt1 + b * N1;
        for (int i = tid; i < N1; i += 256) {
            float4 qq = tp[i];
            sm[i] = make_float4(-2.f * qq.x, -2.f * qq.y, -2.f * qq.z, qq.w);
        }
        __syncthreads();
        int n = (bb & 1) * 256 + tid;
        float4 P = ps1[b * N1 + n];
        float best = FLT_MAX; int bi = 0;
#pragma unroll 16
        for (int m = 0; m < N1; ++m) {
            float4 Q = sm[m];
            float d = fmaf(P.x, Q.x, fmaf(P.y, Q.y, fmaf(P.z, Q.z, Q.w)));
            if (d < best) { best = d; bi = m; }    // ascending m: first-min
        }
        float cosv = cos_pm(sd1T, td1T, (size_t)b * N1 + n, (size_t)b * N1 + bi);
        wave_reduce_atomic(cosv, acc + 1);
    }

    __syncthreads();                               // block's atomics all issued
    if (tid == 0) {
        __threadfence();
        unsigned old = atomicAdd((unsigned*)(acc + 2), 1u);
        if (old == 263u) {                         // last of 264 blocks
            float a0 = atomicAdd(acc + 0, 0.f);
            float a1 = atomicAdd(acc + 1, 0.f);
            out[0] = 1.f - 0.5f * (a0 * (1.f / 16384.f) + a1 * (1.f / 2048.f));
        }
    }
}

extern "C" void kernel_launch(void* const* d_in, const int* in_sizes, int n_in,
                              void* d_out, int out_size, void* d_ws, size_t ws_size,
                              hipStream_t stream) {
    const float* c_src = (const float*)d_in[0];   // [4,3,64,64,64]
    const float* c_tgt = (const float*)d_in[1];
    const float* sd0   = (const float*)d_in[2];   // [4,32,16,16,16]
    const float* td0   = (const float*)d_in[3];
    const float* sd1   = (const float*)d_in[4];   // [4,32,8,8,8]
    const float* td1   = (const float*)d_in[5];
    float* out = (float*)d_out;

    char* ws = (char*)d_ws;
    float* acc  = (float*)ws;                      // [0]=sum0 [1]=sum1 [2]=ticket
    float* t16a = (float*)(ws + 256);              // 786432 floats each
    float* t16b = t16a + 786432;
    float* t8a  = t16b + 786432;                   // 393216 floats each
    float* t8b  = t8a + 393216;
    float4* ps0 = (float4*)(t8b + 393216);         // 16384 float4
    float4* pt0 = ps0 + 16384;
    float4* ps1 = pt0 + 16384;                     // 2048 float4
    float4* pt1 = ps1 + 2048;
    float* sd0T = (float*)(pt1 + 2048);            // 524288 floats each
    float* td0T = sd0T + 524288;
    float* sd1T = td0T + 524288;                   // 65536 floats each
    float* td1T = sd1T + 65536;

    pass1_both<<<dim3(4896, 2), 256, 0, stream>>>(c_src, c_tgt, sd0, td0, sd1, td1,
                                                  t16a, t16b, t8a, t8b,
                                                  sd0T, td0T, sd1T, td1T, acc);
    pass2_both<<<1152, 256, 0, stream>>>(t16a, t16b, t8a, t8b, ps0, pt0, ps1, pt1);
    nn_cos_all<<<264, 256, 65536, stream>>>(ps0, pt0, sd0T, td0T, ps1, pt1,
                                            sd1T, td1T, acc, out);
}